// Round 14
// baseline (211.908 us; speedup 1.0000x reference)
//
#include <hip/hip_runtime.h>
#include <hip/hip_bf16.h>
#include <math.h>
#include <cstdint>
#include <cstddef>

#define B_    2
#define LSEQ  4096
#define H_    16
#define D_    64
#define M_    32      // query blocks (L/128)
#define KB_   64      // key blocks (L/64)
#define TOPK  6       // int(0.1 * 64)
#define SCALE 0.125f  // D^-0.5
#define LOG2E 1.4426950408889634f
#define SCL2  (SCALE * LOG2E)   // folded: S_mfma = S_true*log2e, p = exp2(S_mfma)
#define EPSL  1e-5f
#define SPLIT 32      // lin_stats split-K: 1024 blocks (4/CU). R6 proved atomics
                      // are NOT the bottleneck; SPLIT=32 keeps latency-hiding TLP.
#define PSTR  65

typedef __attribute__((ext_vector_type(8))) short short8;   // 8 x bf16 (4 VGPR)
typedef __attribute__((ext_vector_type(4))) float f32x4;

// lgkm-only fences: LDS producer/consumer needs lgkmcnt, NOT vmcnt. Using raw
// s_barrier avoids __syncthreads' vmcnt(0) drain so prefetch global loads stay
// in flight across barriers (AITER-style pipeline). Per-wave LDS scratch
// (wPs/olS) needs NO fence after the reads (same-wave LDS is in-order).
#define LGKM_FENCE()   __asm__ volatile("s_waitcnt lgkmcnt(0)" ::: "memory")
#define BLOCK_BARRIER() __asm__ volatile("s_waitcnt lgkmcnt(0)\n\ts_barrier" ::: "memory")

// R13: bf16 converts via the SCALAR compiler intrinsic __float2bfloat16 (RNE,
// HW-lowered, ZERO live temporaries — the old bit-twiddle held 2-3 temps per
// convert, which was exactly the ~8-reg overage that made (256,3) spill).
__device__ __forceinline__ short bf16_rne(float x) {
  union { __hip_bfloat16 h; unsigned short u; } cv;
  cv.h = __float2bfloat16(x);
  return (short)cv.u;
}
__device__ __forceinline__ unsigned pack2_rne(float a, float b) {
  return ((unsigned)(unsigned short)bf16_rne(a)) |
         (((unsigned)(unsigned short)bf16_rne(b)) << 16);
}
__device__ __forceinline__ float bf16_to_f32(short s) {
  return __uint_as_float(((unsigned)(unsigned short)s) << 16);
}

// ---------------- Kernel A: linear-branch stats via MFMA + k block pooling ----------------
// (q-pooling removed: the LUT is computed inside sparse_attn from pkw only.)
// V staging uses the R8-proven key-pair trick — thread owns keys (2vj,2vj+1)
// x 8 d's; col(2vj+1)=col(2vj)+1 under the XOR swizzle (2vj even), so each pair
// is one pack2_rne + one aligned ds_write_b32: halves V-scatter converts+stores.
__global__ __launch_bounds__(256) void lin_stats_kernel(
    const float* __restrict__ kin, const float* __restrict__ vin,
    float* __restrict__ kv, float* __restrict__ kfs,
    float* __restrict__ pkw)
{
  int blk   = blockIdx.x;            // B*H*SPLIT
  int chunk = blk & (SPLIT - 1);
  int bh    = blk / SPLIT;
  int h = bh & (H_ - 1);
  int b = bh >> 4;
  int tid = threadIdx.x;
  int w = tid >> 6, lane = tid & 63, quad = lane >> 4, l15 = lane & 15;
  const int vj = tid & 31, vd0 = (tid >> 5) * 8;   // V pairing: 32 key-pairs x 8 d-octets

  __shared__ __align__(16) float kraw[64 * 68];
  __shared__ __align__(16) short sA[64 * 64];
  __shared__ __align__(16) short sB[80 * 64];
  __shared__ float pred[512];

  for (int i = tid; i < 1024; i += 256) {
    int row = 64 + (i >> 6);
    sB[row * 64 + (i & 63)] = (row == 64) ? (short)0x3F80 : (short)0;
  }

  f32x4 acc[5];
#pragma unroll
  for (int nt = 0; nt < 5; nt++) acc[nt] = (f32x4){0.f, 0.f, 0.f, 0.f};

  for (int t2 = 0; t2 < 64 / SPLIT; ++t2) {
    int kbs = chunk * (64 / SPLIT) + t2;   // key-block index 0..63
    int l0  = kbs * 64;                    // row offset of this 64-row tile
    BLOCK_BARRIER();
#pragma unroll
    for (int i = 0; i < 4; i++) {
      int f = tid + i * 256;
      int row = f >> 4, c4 = f & 15;
      *(float4*)(kraw + row * 68 + c4 * 4) =
        *(const float4*)(kin + (((size_t)b * LSEQ + l0 + row) * H_ + h) * D_ + c4 * 4);
    }
    {
      const float* vpE = vin + (((size_t)b * LSEQ + l0 + 2 * vj) * H_ + h) * D_ + vd0;
      float4 a0 = *(const float4*)(vpE + 0);
      float4 a1 = *(const float4*)(vpE + 4);
      float4 a2 = *(const float4*)(vpE + H_ * D_);
      float4 a3 = *(const float4*)(vpE + H_ * D_ + 4);
      float fa[8] = {a0.x,a0.y,a0.z,a0.w, a1.x,a1.y,a1.z,a1.w};  // key 2*vj
      float fb[8] = {a2.x,a2.y,a2.z,a2.w, a3.x,a3.y,a3.z,a3.w};  // key 2*vj+1
      int khi = (2 * vj) >> 3, klo = (2 * vj) & 7;   // klo even -> b32-aligned col
#pragma unroll
      for (int jj = 0; jj < 8; jj++) {
        int e = vd0 + jj;
        int col = ((khi ^ (e & 7)) << 3) | klo;
        *(unsigned*)(sB + e * 64 + col) = pack2_rne(fa[jj], fb[jj]);
      }
    }
    BLOCK_BARRIER();
    {
      float kp = 0.f;
#pragma unroll
      for (int i = 0; i < 16; i++) kp += kraw[(w * 16 + i) * 68 + lane];
      pred[256 + w * 64 + lane] = kp;
    }
    float kr[16];
    *(float4*)(kr + 0)  = *(const float4*)(kraw + lane * 68 + w * 16 + 0);
    *(float4*)(kr + 4)  = *(const float4*)(kraw + lane * 68 + w * 16 + 4);
    *(float4*)(kr + 8)  = *(const float4*)(kraw + lane * 68 + w * 16 + 8);
    *(float4*)(kr + 12) = *(const float4*)(kraw + lane * 68 + w * 16 + 12);
    float ps = 0.f;
#pragma unroll
    for (int j = 0; j < 16; j++) { kr[j] = __expf(kr[j]); ps += kr[j]; }
    pred[w * 64 + lane] = ps;
    BLOCK_BARRIER();
    float ssum = pred[lane] + pred[64 + lane] + pred[128 + lane] + pred[192 + lane];
    float scl = 1.f / ssum;
    if (tid < 64) {
      float s = pred[256 + tid] + pred[320 + tid] + pred[384 + tid] + pred[448 + tid];
      pkw[((size_t)bh * 64 + kbs) * 64 + tid] = s * (1.f / 64.f);
    }
#pragma unroll
    for (int j = 0; j < 16; j++) {
      int d = w * 16 + j;
      int col = (((lane >> 3) ^ (d & 7)) << 3) | (lane & 7);
      sA[d * 64 + col] = bf16_rne(kr[j] * scl);
    }
    BLOCK_BARRIER();
    short8 af[2];
#pragma unroll
    for (int ks = 0; ks < 2; ks++) {
      int row = w * 16 + l15;
      int bi = (ks * 4 + quad) ^ (row & 7);
      af[ks] = *(const short8*)(sA + row * 64 + bi * 8);
    }
#pragma unroll
    for (int nt = 0; nt < 5; nt++) {
      int row = nt * 16 + l15;
#pragma unroll
      for (int ks = 0; ks < 2; ks++) {
        int bi = (ks * 4 + quad) ^ (row & 7);
        short8 bf = *(const short8*)(sB + row * 64 + bi * 8);
        acc[nt] = __builtin_amdgcn_mfma_f32_16x16x32_bf16(af[ks], bf, acc[nt], 0, 0, 0);
      }
    }
  }
  size_t kvb = (size_t)bh * 4096;
  int d0 = w * 16 + quad * 4;
#pragma unroll
  for (int nt = 0; nt < 4; nt++)
#pragma unroll
    for (int r = 0; r < 4; r++)
      atomicAdd(&kv[kvb + (size_t)(d0 + r) * 64 + nt * 16 + l15], acc[nt][r]);
  if (l15 == 0) {
#pragma unroll
    for (int r = 0; r < 4; r++)
      atomicAdd(&kfs[bh * 64 + d0 + r], acc[4][r]);
  }
}

// ---------------- Kernel B: fused LUT + MFMA block-sparse attention + linear branch ----------------
// R14 experiment: (256,3) RETRY with the R13 HW-convert code. The three prior
// (256,3) failures spilled EXACTLY 8 dwords/thread; the old bit-twiddle convert
// held 2-3 live temps x 16 in-flight converts at the K-pack peak — the HW
// convert holds zero, plausibly freeing exactly that overage. Failure signature
// is unambiguous (WRITE_SIZE > 32768 KB): if it appears, revert to (256,2)/R13.
// Other closed lines: 2-deep prefetch regressed (R9, K/V are L2 hits via XCD
// swizzle); SPLIT/atomic tuning closed (R6); hand-asm cvt_pk broken (R11).
__global__ __launch_bounds__(256, 3) void sparse_attn_kernel(
    const float* __restrict__ qin, const float* __restrict__ kin,
    const float* __restrict__ vin, const float* __restrict__ pkw,
    const float* __restrict__ kv, const float* __restrict__ kfs,
    const float* __restrict__ Wg, const float* __restrict__ biasg,
    float* __restrict__ out)
{
  // XCD-locality swizzle
  int blk = blockIdx.x;           // B*H*M
  int x = blk & 7, g = blk >> 3;
  int bh = x * 4 + (g & 3);
  int m  = g >> 2;
  int h = bh & (H_ - 1);
  int b = bh >> 4;
  int t = threadIdx.x;
  int w = t >> 6, lane = t & 63, quad = lane >> 4, l15 = lane & 15;

  __shared__ __align__(16) char smem[37120];
  short* sK  = (short*)smem;               // [64*64]  K  [key][d] swizzled           (0..8192)
  short* sV  = (short*)(smem + 8192);      // [80*64]  V^T [d][key] + ones row d=64   (8192..18432)
  short* sP  = (short*)(smem + 18432);     // [4][16*64] per-wave P scratch           (18432..26624)
  // prologue aliases (all reads done before ones-init / main loop):
  float* pkL  = (float*)smem;              // [64][65] pooled-k rows                  (0..16640)
  float4* qps = (float4*)(smem + 16640);   // [256] q-pool partials                   (16640..20736)
  float* pqL  = (float*)(smem + 20736);    // [64] pooled q row                       (20736..20992)
  // epilogue aliases:
  short* skv  = (short*)(smem + 18432);    // [80*64] kv^T [e][d] + kfs row e=64
  short* sW   = (short*)(smem + 28672);    // [64*64] W [e][d]
  float* sbias= (float*)(smem + 36864);    // [64]
  short* wPs = sP + w * 1024;
  short* olS = (short*)smem + w * 1024;    // epilogue per-wave o_l scratch (over sK)

  // ---- prologue: stage pooled-k + q-pool partials ----
#pragma unroll
  for (int i = 0; i < 16; i++) {
    int o = t + i * 256;
    pkL[(o >> 6) * PSTR + (o & 63)] = pkw[(size_t)bh * 4096 + o];
  }
  {
    int c4 = t & 15, r0 = t >> 4;
    float4 sacc = {0.f, 0.f, 0.f, 0.f};
#pragma unroll
    for (int i = 0; i < 8; i++) {
      int row = m * 128 + r0 + i * 16;
      float4 xq = *(const float4*)(qin + (((size_t)b * LSEQ + row) * H_ + h) * D_ + c4 * 4);
      sacc.x += xq.x; sacc.y += xq.y; sacc.z += xq.z; sacc.w += xq.w;
    }
    qps[t] = sacc;
  }
  BLOCK_BARRIER();
  if (t < 64) {
    const float* qf = (const float*)qps;
    float sY = 0.f;
#pragma unroll
    for (int j = 0; j < 16; j++) sY += qf[j * 64 + t];
    pqL[t] = sY;
  }
  BLOCK_BARRIER();
  // ---- per-wave (redundant) score + top-6; lane == key-block ----
  float scv = 0.f;
  {
    const float* rowp = pkL + lane * PSTR;
#pragma unroll
    for (int d = 0; d < 64; d++) scv += pqL[d] * rowp[d];
  }
  int kbs_[TOPK];
#pragma unroll
  for (int r = 0; r < TOPK; r++) {
    float bs = scv; int bi = lane;
#pragma unroll
    for (int off = 32; off; off >>= 1) {
      float os = __shfl_xor(bs, off);
      int   oi = __shfl_xor(bi, off);
      if (os > bs || (os == bs && oi < bi)) { bs = os; bi = oi; }
    }
    int bsel = __builtin_amdgcn_readfirstlane(bi);  // lane-uniform -> SGPR
    kbs_[r] = bsel;                     // matches lax.top_k tie-break (lower idx first)
    if (lane == bsel) scv = -INFINITY;
  }
  BLOCK_BARRIER();   // all pkL/pqL reads done before ones-init overwrites [16384,16640)

  // ones rows d=64..79 of sV (never restaged)
  for (int i = t; i < 1024; i += 256) {
    int row = 64 + (i >> 6);
    sV[row * 64 + (i & 63)] = (row == 64) ? (short)0x3F80 : (short)0;
  }

  // ---- Q fragments (scaled by SCALE*log2e, single bf16) ----
  short8 qA[2][2];
#pragma unroll
  for (int mt = 0; mt < 2; mt++) {
    int qrow = m * 128 + w * 32 + mt * 16 + l15;
    const float* qp = qin + (((size_t)b * LSEQ + qrow) * H_ + h) * D_;
#pragma unroll
    for (int ks = 0; ks < 2; ks++) {
      int d0 = ks * 32 + quad * 8;
      float4 a0 = *(const float4*)(qp + d0);
      float4 a1 = *(const float4*)(qp + d0 + 4);
      union { int4 i; short8 s; } u;
      u.i.x = (int)pack2_rne(a0.x * SCL2, a0.y * SCL2);
      u.i.y = (int)pack2_rne(a0.z * SCL2, a0.w * SCL2);
      u.i.z = (int)pack2_rne(a1.x * SCL2, a1.y * SCL2);
      u.i.w = (int)pack2_rne(a1.z * SCL2, a1.w * SCL2);
      qA[mt][ks] = u.s;
    }
  }

  f32x4 O[2][4];
  f32x4 Lacc[2];
#pragma unroll
  for (int mt = 0; mt < 2; mt++) {
#pragma unroll
    for (int dt = 0; dt < 4; dt++) O[mt][dt] = (f32x4){0.f, 0.f, 0.f, 0.f};
    Lacc[mt] = (f32x4){0.f, 0.f, 0.f, 0.f};
  }

  // prefetch registers (raw fp32, packed at store time next iter)
  float4 pk0, pk1, pk2, pk3;   // K: thread (key=t>>2, c=t&3) 16 d's
  float4 pv0, pv1, pv2, pv3;   // V: keys (2*vj, 2*vj+1), d in [vd0, vd0+8)
  const int kkey = t >> 2, kc = t & 3;
  const int vj = t & 31, vd0 = (t >> 5) * 8;   // V pairing: 32 key-pairs x 8 d-octets

  {
    int kb = kbs_[0];
    const float* kp = kin + (((size_t)b * LSEQ + (size_t)kb * 64 + kkey) * H_ + h) * D_ + kc * 16;
    pk0 = *(const float4*)(kp + 0);  pk1 = *(const float4*)(kp + 4);
    pk2 = *(const float4*)(kp + 8);  pk3 = *(const float4*)(kp + 12);
    const float* vpE = vin + (((size_t)b * LSEQ + (size_t)kb * 64 + 2 * vj) * H_ + h) * D_ + vd0;
    pv0 = *(const float4*)(vpE + 0);       pv1 = *(const float4*)(vpE + 4);
    pv2 = *(const float4*)(vpE + H_ * D_); pv3 = *(const float4*)(vpE + H_ * D_ + 4);
  }

#pragma unroll
  for (int s = 0; s < TOPK; s++) {
    BLOCK_BARRIER();   // prev iter's LDS reads done (lgkm only — prefetch stays in flight)
    // ---- store prefetched K (pack + b128) ----
    {
      int4 h0, h1;
      h0.x = (int)pack2_rne(pk0.x, pk0.y);  h0.y = (int)pack2_rne(pk0.z, pk0.w);
      h0.z = (int)pack2_rne(pk1.x, pk1.y);  h0.w = (int)pack2_rne(pk1.z, pk1.w);
      h1.x = (int)pack2_rne(pk2.x, pk2.y);  h1.y = (int)pack2_rne(pk2.z, pk2.w);
      h1.z = (int)pack2_rne(pk3.x, pk3.y);  h1.w = (int)pack2_rne(pk3.z, pk3.w);
      int base = kkey * 64;
      int b0 = ((kc * 2    ) ^ (kkey & 7)) << 3;
      int b1 = ((kc * 2 + 1) ^ (kkey & 7)) << 3;
      *(int4*)(sK + base + b0) = h0;
      *(int4*)(sK + base + b1) = h1;
    }
    // ---- store prefetched V (paired bf16x2 transpose scatter) ----
    {
      float fa[8] = {pv0.x,pv0.y,pv0.z,pv0.w, pv1.x,pv1.y,pv1.z,pv1.w};  // key 2*vj
      float fb[8] = {pv2.x,pv2.y,pv2.z,pv2.w, pv3.x,pv3.y,pv3.z,pv3.w};  // key 2*vj+1
      int khi = (2 * vj) >> 3, klo = (2 * vj) & 7;   // klo even -> b32-aligned col
#pragma unroll
      for (int jj = 0; jj < 8; jj++) {
        int d = vd0 + jj;
        int col = ((khi ^ (d & 7)) << 3) | klo;
        *(unsigned*)(sV + d * 64 + col) = pack2_rne(fa[jj], fb[jj]);
      }
    }
    BLOCK_BARRIER();   // staged data visible (lgkm only)
    // ---- issue next iter's prefetch (overlaps with MFMA phase below) ----
    if (s + 1 < TOPK) {
      int kb = kbs_[s + 1];
      const float* kp = kin + (((size_t)b * LSEQ + (size_t)kb * 64 + kkey) * H_ + h) * D_ + kc * 16;
      pk0 = *(const float4*)(kp + 0);  pk1 = *(const float4*)(kp + 4);
      pk2 = *(const float4*)(kp + 8);  pk3 = *(const float4*)(kp + 12);
      const float* vpE = vin + (((size_t)b * LSEQ + (size_t)kb * 64 + 2 * vj) * H_ + h) * D_ + vd0;
      pv0 = *(const float4*)(vpE + 0);       pv1 = *(const float4*)(vpE + 4);
      pv2 = *(const float4*)(vpE + H_ * D_); pv3 = *(const float4*)(vpE + H_ * D_ + 4);
    }

#pragma unroll
    for (int mt = 0; mt < 2; mt++) {
      // ---- S = Q K^T (S is already *log2e scaled) ----
      f32x4 S[4];
      __builtin_amdgcn_s_setprio(1);
#pragma unroll
      for (int nt = 0; nt < 4; nt++) {
        f32x4 acc = (f32x4){0.f, 0.f, 0.f, 0.f};
        int row = nt * 16 + l15;
#pragma unroll
        for (int ks = 0; ks < 2; ks++) {
          int blk8 = ((ks * 4 + quad) ^ (row & 7)) << 3;
          short8 kh = *(const short8*)(sK + row * 64 + blk8);
          acc = __builtin_amdgcn_mfma_f32_16x16x32_bf16(qA[mt][ks], kh, acc, 0, 0, 0);
        }
        S[nt] = acc;
      }
      __builtin_amdgcn_s_setprio(0);
      // ---- p = exp2(S), wave-local transpose ----
#pragma unroll
      for (int r = 0; r < 4; r++) {
        int prow = quad * 4 + r;
#pragma unroll
        for (int nt = 0; nt < 4; nt++) {
          int key = nt * 16 + l15;
          int idx = prow * 64 + ((((key >> 3) ^ (prow & 7)) << 3) | (key & 7));
          wPs[idx] = bf16_rne(__builtin_amdgcn_exp2f(S[nt][r]));
        }
      }
      LGKM_FENCE();
      short8 pA[2];
#pragma unroll
      for (int ks = 0; ks < 2; ks++) {
        int blk8 = ((ks * 4 + quad) ^ (l15 & 7)) << 3;
        pA[ks] = *(const short8*)(wPs + l15 * 64 + blk8);
      }
      // (no fence needed after per-wave-scratch reads: same-wave LDS is in-order)
      // ---- O += P V  (dt=4 tile = ones row -> Lacc) ----
      __builtin_amdgcn_s_setprio(1);
#pragma unroll
      for (int dt = 0; dt < 5; dt++) {
        f32x4 acc = (dt < 4) ? O[mt][dt] : Lacc[mt];
        int row = dt * 16 + l15;
#pragma unroll
        for (int ks = 0; ks < 2; ks++) {
          int blk8 = ((ks * 4 + quad) ^ (row & 7)) << 3;
          short8 vh = *(const short8*)(sV + row * 64 + blk8);
          acc = __builtin_amdgcn_mfma_f32_16x16x32_bf16(pA[ks], vh, acc, 0, 0, 0);
        }
        if (dt < 4) O[mt][dt] = acc; else Lacc[mt] = acc;
      }
      __builtin_amdgcn_s_setprio(0);
    } // mt
  } // kblocks

  // ---- normalize o_s by l (l at l15==0 cols of each quad) ----
#pragma unroll
  for (int mt = 0; mt < 2; mt++)
#pragma unroll
    for (int r = 0; r < 4; r++) {
      float lv = __shfl(Lacc[mt][r], lane & 48);
      float inv = 1.f / lv;
#pragma unroll
      for (int dt = 0; dt < 4; dt++) O[mt][dt][r] *= inv;
    }

  // ---- epilogue: linear branch fused (qf from register Q-frags) ----
  BLOCK_BARRIER();   // main-loop LDS reads done; aliases writable
#pragma unroll
  for (int i = 0; i < 16; i++) {
    int idx = t + i * 256;
    int d = idx >> 6, e = idx & 63;
    int c1 = (((d >> 3) ^ (e & 7)) << 3) | (d & 7);
    skv[e * 64 + c1] = bf16_rne(kv[(size_t)bh * 4096 + idx]);
    int eo = idx >> 6, dd = idx & 63;
    int c2 = (((dd >> 3) ^ (eo & 7)) << 3) | (dd & 7);
    sW[eo * 64 + c2] = bf16_rne(Wg[idx]);
  }
#pragma unroll
  for (int j = 0; j < 4; j++) {
    int idx2 = t + j * 256;
    int row = 64 + (idx2 >> 6), col = idx2 & 63;
    skv[row * 64 + col] = (row == 64) ? bf16_rne(kfs[bh * 64 + col]) : (short)0;
  }
  if (t < 64) sbias[t] = biasg[t];
  BLOCK_BARRIER();

  const short8 onesB = {(short)0x3F80,(short)0x3F80,(short)0x3F80,(short)0x3F80,
                        (short)0x3F80,(short)0x3F80,(short)0x3F80,(short)0x3F80};

#pragma unroll
  for (int mt = 0; mt < 2; mt++) {
    // expq = e^q = exp2(8 * qA) elementwise (qA = q*0.125*log2e)
    float eq[2][8];
    short8 eqs[2];
#pragma unroll
    for (int ks = 0; ks < 2; ks++) {
      union { short8 s; short a[8]; } uu; uu.s = qA[mt][ks];
      union { int4 i; short8 s; } pp;
#pragma unroll
      for (int j = 0; j < 8; j++)
        eq[ks][j] = __builtin_amdgcn_exp2f(8.f * bf16_to_f32(uu.a[j]));
      pp.i.x = (int)pack2_rne(eq[ks][0], eq[ks][1]);
      pp.i.y = (int)pack2_rne(eq[ks][2], eq[ks][3]);
      pp.i.z = (int)pack2_rne(eq[ks][4], eq[ks][5]);
      pp.i.w = (int)pack2_rne(eq[ks][6], eq[ks][7]);
      eqs[ks] = pp.s;
    }
    // row sums via ones-B MFMA
    f32x4 ssv = (f32x4){0.f, 0.f, 0.f, 0.f};
    ssv = __builtin_amdgcn_mfma_f32_16x16x32_bf16(eqs[0], onesB, ssv, 0, 0, 0);
    ssv = __builtin_amdgcn_mfma_f32_16x16x32_bf16(eqs[1], onesB, ssv, 0, 0, 0);
    int srcl = (l15 >> 2) << 4;
    float s0 = __shfl(ssv[0], srcl);
    float s1 = __shfl(ssv[1], srcl);
    float s2 = __shfl(ssv[2], srcl);
    float s3 = __shfl(ssv[3], srcl);
    int rr = l15 & 3;
    float ssrow = (rr == 0) ? s0 : (rr == 1) ? s1 : (rr == 2) ? s2 : s3;
    float qinv = 1.f / ssrow;
    // qf A-frags
    short8 qf[2];
#pragma unroll
    for (int ks = 0; ks < 2; ks++) {
      union { int4 i; short8 s; } pp;
      pp.i.x = (int)pack2_rne(eq[ks][0] * qinv, eq[ks][1] * qinv);
      pp.i.y = (int)pack2_rne(eq[ks][2] * qinv, eq[ks][3] * qinv);
      pp.i.z = (int)pack2_rne(eq[ks][4] * qinv, eq[ks][5] * qinv);
      pp.i.w = (int)pack2_rne(eq[ks][6] * qinv, eq[ks][7] * qinv);
      qf[ks] = pp.s;
    }
    // num (nt 0..3) and den (nt=4, kfs row)
    f32x4 Cn[5];
#pragma unroll
    for (int nt = 0; nt < 5; nt++) {
      f32x4 acc = (f32x4){0.f, 0.f, 0.f, 0.f};
      int row = nt * 16 + l15;
#pragma unroll
      for (int ks = 0; ks < 2; ks++) {
        int blk8 = ((ks * 4 + quad) ^ (row & 7)) << 3;
        short8 bf = *(const short8*)(skv + row * 64 + blk8);
        acc = __builtin_amdgcn_mfma_f32_16x16x32_bf16(qf[ks], bf, acc, 0, 0, 0);
      }
      Cn[nt] = acc;
    }
    // o_l = num / (eps + den) -> wave-local transpose
#pragma unroll
    for (int r = 0; r < 4; r++) {
      float dv = __shfl(Cn[4][r], lane & 48);
      float invd = 1.f / (EPSL + dv);
      int prow = quad * 4 + r;
#pragma unroll
      for (int nt = 0; nt < 4; nt++) {
        int e = nt * 16 + l15;
        int idx = prow * 64 + ((((e >> 3) ^ (prow & 7)) << 3) | (e & 7));
        olS[idx] = bf16_rne(Cn[nt][r] * invd);
      }
    }
    LGKM_FENCE();
    short8 oh[2];
#pragma unroll
    for (int ks = 0; ks < 2; ks++) {
      int blk8 = ((ks * 4 + quad) ^ (l15 & 7)) << 3;
      oh[ks] = *(const short8*)(olS + l15 * 64 + blk8);
    }
    // (no fence needed after per-wave-scratch reads)
    // O += o_l @ W^T
#pragma unroll
    for (int nt = 0; nt < 4; nt++) {
      int row = nt * 16 + l15;
      f32x4 acc = O[mt][nt];
#pragma unroll
      for (int ks = 0; ks < 2; ks++) {
        int blk8 = ((ks * 4 + quad) ^ (row & 7)) << 3;
        short8 wf = *(const short8*)(sW + row * 64 + blk8);
        acc = __builtin_amdgcn_mfma_f32_16x16x32_bf16(oh[ks], wf, acc, 0, 0, 0);
      }
      O[mt][nt] = acc;
    }
  }

  // ---- store out = o_s + o_l + bias ----
#pragma unroll
  for (int mt = 0; mt < 2; mt++) {
    int qrow0 = m * 128 + w * 32 + mt * 16 + quad * 4;
#pragma unroll
    for (int r = 0; r < 4; r++) {
      float* op = out + (((size_t)b * LSEQ + qrow0 + r) * H_ + h) * D_ + l15;
#pragma unroll
      for (int dt = 0; dt < 4; dt++)
        op[dt * 16] = O[mt][dt][r] + sbias[dt * 16 + l15];
    }
  }
}

extern "C" void kernel_launch(void* const* d_in, const int* in_sizes, int n_in,
                              void* d_out, int out_size, void* d_ws, size_t ws_size,
                              hipStream_t stream)
{
  const float* q    = (const float*)d_in[0];
  const float* k    = (const float*)d_in[1];
  const float* v    = (const float*)d_in[2];
  const float* W    = (const float*)d_in[3];
  const float* bias = (const float*)d_in[4];
  float* out = (float*)d_out;

  float* kv  = (float*)d_ws;                               // B*H*64*64
  float* kfs = kv  + (size_t)B_ * H_ * D_ * D_;            // B*H*64
  float* pkw = kfs + (size_t)B_ * H_ * D_;                 // B*H*64*64

  size_t zero_bytes = ((size_t)B_ * H_ * D_ * D_ + (size_t)B_ * H_ * D_) * sizeof(float);
  (void)hipMemsetAsync(d_ws, 0, zero_bytes, stream);

  hipLaunchKernelGGL(lin_stats_kernel,  dim3(B_ * H_ * SPLIT), dim3(256), 0, stream,
                     k, v, kv, kfs, pkw);
  hipLaunchKernelGGL(sparse_attn_kernel,dim3(B_ * H_ * M_),    dim3(256), 0, stream,
                     q, k, v, pkw, kv, kfs, W, bias, out);
}

// Round 15
// 200.639 us; speedup vs baseline: 1.0562x; 1.0562x over previous
//
#include <hip/hip_runtime.h>
#include <hip/hip_bf16.h>
#include <math.h>
#include <cstdint>
#include <cstddef>

#define B_    2
#define LSEQ  4096
#define H_    16
#define D_    64
#define M_    32      // query blocks (L/128)
#define KB_   64      // key blocks (L/64)
#define TOPK  6       // int(0.1 * 64)
#define SCALE 0.125f  // D^-0.5
#define LOG2E 1.4426950408889634f
#define SCL2  (SCALE * LOG2E)   // folded: S_mfma = S_true*log2e, p = exp2(S_mfma)
#define EPSL  1e-5f
#define SPLIT 32      // lin_stats split-K: 1024 blocks (4/CU). R6 proved atomics
                      // are NOT the bottleneck; SPLIT=32 keeps latency-hiding TLP.
#define PSTR  65

typedef __attribute__((ext_vector_type(8))) short short8;   // 8 x bf16 (4 VGPR)
typedef __attribute__((ext_vector_type(4))) float f32x4;

// lgkm-only fences: LDS producer/consumer needs lgkmcnt, NOT vmcnt. Using raw
// s_barrier avoids __syncthreads' vmcnt(0) drain so prefetch global loads stay
// in flight across barriers (AITER-style pipeline). Per-wave LDS scratch
// (wPs/olS) needs NO fence after the reads (same-wave LDS is in-order).
#define LGKM_FENCE()   __asm__ volatile("s_waitcnt lgkmcnt(0)" ::: "memory")
#define BLOCK_BARRIER() __asm__ volatile("s_waitcnt lgkmcnt(0)\n\ts_barrier" ::: "memory")

// bf16 converts via the SCALAR compiler intrinsic __float2bfloat16 (RNE,
// HW-lowered). R11's hand-asm cvt_pk mis-ordered halves (refcheck fail);
// R12's pair intrinsic doesn't exist in ROCm 7.2. This form verified in R13:
// VALUBusy 31->27%, sparse_attn 71->66us, absmax unchanged.
__device__ __forceinline__ short bf16_rne(float x) {
  union { __hip_bfloat16 h; unsigned short u; } cv;
  cv.h = __float2bfloat16(x);
  return (short)cv.u;
}
__device__ __forceinline__ unsigned pack2_rne(float a, float b) {
  return ((unsigned)(unsigned short)bf16_rne(a)) |
         (((unsigned)(unsigned short)bf16_rne(b)) << 16);
}
__device__ __forceinline__ float bf16_to_f32(short s) {
  return __uint_as_float(((unsigned)(unsigned short)s) << 16);
}

// ---------------- Kernel A: linear-branch stats via MFMA + k block pooling ----------------
// (q-pooling removed: the LUT is computed inside sparse_attn from pkw only.)
// V staging uses the R8-proven key-pair trick — thread owns keys (2vj,2vj+1)
// x 8 d's; col(2vj+1)=col(2vj)+1 under the XOR swizzle (2vj even), so each pair
// is one pack2_rne + one aligned ds_write_b32: halves V-scatter converts+stores.
__global__ __launch_bounds__(256) void lin_stats_kernel(
    const float* __restrict__ kin, const float* __restrict__ vin,
    float* __restrict__ kv, float* __restrict__ kfs,
    float* __restrict__ pkw)
{
  int blk   = blockIdx.x;            // B*H*SPLIT
  int chunk = blk & (SPLIT - 1);
  int bh    = blk / SPLIT;
  int h = bh & (H_ - 1);
  int b = bh >> 4;
  int tid = threadIdx.x;
  int w = tid >> 6, lane = tid & 63, quad = lane >> 4, l15 = lane & 15;
  const int vj = tid & 31, vd0 = (tid >> 5) * 8;   // V pairing: 32 key-pairs x 8 d-octets

  __shared__ __align__(16) float kraw[64 * 68];
  __shared__ __align__(16) short sA[64 * 64];
  __shared__ __align__(16) short sB[80 * 64];
  __shared__ float pred[512];

  for (int i = tid; i < 1024; i += 256) {
    int row = 64 + (i >> 6);
    sB[row * 64 + (i & 63)] = (row == 64) ? (short)0x3F80 : (short)0;
  }

  f32x4 acc[5];
#pragma unroll
  for (int nt = 0; nt < 5; nt++) acc[nt] = (f32x4){0.f, 0.f, 0.f, 0.f};

  for (int t2 = 0; t2 < 64 / SPLIT; ++t2) {
    int kbs = chunk * (64 / SPLIT) + t2;   // key-block index 0..63
    int l0  = kbs * 64;                    // row offset of this 64-row tile
    BLOCK_BARRIER();
#pragma unroll
    for (int i = 0; i < 4; i++) {
      int f = tid + i * 256;
      int row = f >> 4, c4 = f & 15;
      *(float4*)(kraw + row * 68 + c4 * 4) =
        *(const float4*)(kin + (((size_t)b * LSEQ + l0 + row) * H_ + h) * D_ + c4 * 4);
    }
    {
      const float* vpE = vin + (((size_t)b * LSEQ + l0 + 2 * vj) * H_ + h) * D_ + vd0;
      float4 a0 = *(const float4*)(vpE + 0);
      float4 a1 = *(const float4*)(vpE + 4);
      float4 a2 = *(const float4*)(vpE + H_ * D_);
      float4 a3 = *(const float4*)(vpE + H_ * D_ + 4);
      float fa[8] = {a0.x,a0.y,a0.z,a0.w, a1.x,a1.y,a1.z,a1.w};  // key 2*vj
      float fb[8] = {a2.x,a2.y,a2.z,a2.w, a3.x,a3.y,a3.z,a3.w};  // key 2*vj+1
      int khi = (2 * vj) >> 3, klo = (2 * vj) & 7;   // klo even -> b32-aligned col
#pragma unroll
      for (int jj = 0; jj < 8; jj++) {
        int e = vd0 + jj;
        int col = ((khi ^ (e & 7)) << 3) | klo;
        *(unsigned*)(sB + e * 64 + col) = pack2_rne(fa[jj], fb[jj]);
      }
    }
    BLOCK_BARRIER();
    {
      float kp = 0.f;
#pragma unroll
      for (int i = 0; i < 16; i++) kp += kraw[(w * 16 + i) * 68 + lane];
      pred[256 + w * 64 + lane] = kp;
    }
    float kr[16];
    *(float4*)(kr + 0)  = *(const float4*)(kraw + lane * 68 + w * 16 + 0);
    *(float4*)(kr + 4)  = *(const float4*)(kraw + lane * 68 + w * 16 + 4);
    *(float4*)(kr + 8)  = *(const float4*)(kraw + lane * 68 + w * 16 + 8);
    *(float4*)(kr + 12) = *(const float4*)(kraw + lane * 68 + w * 16 + 12);
    float ps = 0.f;
#pragma unroll
    for (int j = 0; j < 16; j++) { kr[j] = __expf(kr[j]); ps += kr[j]; }
    pred[w * 64 + lane] = ps;
    BLOCK_BARRIER();
    float ssum = pred[lane] + pred[64 + lane] + pred[128 + lane] + pred[192 + lane];
    float scl = 1.f / ssum;
    if (tid < 64) {
      float s = pred[256 + tid] + pred[320 + tid] + pred[384 + tid] + pred[448 + tid];
      pkw[((size_t)bh * 64 + kbs) * 64 + tid] = s * (1.f / 64.f);
    }
#pragma unroll
    for (int j = 0; j < 16; j++) {
      int d = w * 16 + j;
      int col = (((lane >> 3) ^ (d & 7)) << 3) | (lane & 7);
      sA[d * 64 + col] = bf16_rne(kr[j] * scl);
    }
    BLOCK_BARRIER();
    short8 af[2];
#pragma unroll
    for (int ks = 0; ks < 2; ks++) {
      int row = w * 16 + l15;
      int bi = (ks * 4 + quad) ^ (row & 7);
      af[ks] = *(const short8*)(sA + row * 64 + bi * 8);
    }
#pragma unroll
    for (int nt = 0; nt < 5; nt++) {
      int row = nt * 16 + l15;
#pragma unroll
      for (int ks = 0; ks < 2; ks++) {
        int bi = (ks * 4 + quad) ^ (row & 7);
        short8 bf = *(const short8*)(sB + row * 64 + bi * 8);
        acc[nt] = __builtin_amdgcn_mfma_f32_16x16x32_bf16(af[ks], bf, acc[nt], 0, 0, 0);
      }
    }
  }
  size_t kvb = (size_t)bh * 4096;
  int d0 = w * 16 + quad * 4;
#pragma unroll
  for (int nt = 0; nt < 4; nt++)
#pragma unroll
    for (int r = 0; r < 4; r++)
      atomicAdd(&kv[kvb + (size_t)(d0 + r) * 64 + nt * 16 + l15], acc[nt][r]);
  if (l15 == 0) {
#pragma unroll
    for (int r = 0; r < 4; r++)
      atomicAdd(&kfs[bh * 64 + d0 + r], acc[4][r]);
  }
}

// ---------------- Kernel B: fused LUT + MFMA block-sparse attention + linear branch ----------------
// R13-proven configuration (66us, zero spill, total 201us): (256,2) + 1-deep
// joint K+V prefetch + paired V staging + HW bf16 converts.
// CLOSED LINES (measured): (256,3) infeasible — FOUR attempts spilled
// (R3/R4/R7 at 8-11 dwords/thread with bit-twiddle converts; R14 at 4.25
// dwords/thread even with HW converts; kernel needs ~104 arch VGPRs vs ~85
// budget). 2-deep prefetch regressed (R9: gathered K/V are L2 hits via the XCD
// swizzle, 1-deep covers the latency). Atomic tuning closed (R6). Hand-asm
// cvt_pk broken (R11). This is the practical floor of this decomposition.
__global__ __launch_bounds__(256, 2) void sparse_attn_kernel(
    const float* __restrict__ qin, const float* __restrict__ kin,
    const float* __restrict__ vin, const float* __restrict__ pkw,
    const float* __restrict__ kv, const float* __restrict__ kfs,
    const float* __restrict__ Wg, const float* __restrict__ biasg,
    float* __restrict__ out)
{
  // XCD-locality swizzle
  int blk = blockIdx.x;           // B*H*M
  int x = blk & 7, g = blk >> 3;
  int bh = x * 4 + (g & 3);
  int m  = g >> 2;
  int h = bh & (H_ - 1);
  int b = bh >> 4;
  int t = threadIdx.x;
  int w = t >> 6, lane = t & 63, quad = lane >> 4, l15 = lane & 15;

  __shared__ __align__(16) char smem[37120];
  short* sK  = (short*)smem;               // [64*64]  K  [key][d] swizzled           (0..8192)
  short* sV  = (short*)(smem + 8192);      // [80*64]  V^T [d][key] + ones row d=64   (8192..18432)
  short* sP  = (short*)(smem + 18432);     // [4][16*64] per-wave P scratch           (18432..26624)
  // prologue aliases (all reads done before ones-init / main loop):
  float* pkL  = (float*)smem;              // [64][65] pooled-k rows                  (0..16640)
  float4* qps = (float4*)(smem + 16640);   // [256] q-pool partials                   (16640..20736)
  float* pqL  = (float*)(smem + 20736);    // [64] pooled q row                       (20736..20992)
  // epilogue aliases:
  short* skv  = (short*)(smem + 18432);    // [80*64] kv^T [e][d] + kfs row e=64
  short* sW   = (short*)(smem + 28672);    // [64*64] W [e][d]
  float* sbias= (float*)(smem + 36864);    // [64]
  short* wPs = sP + w * 1024;
  short* olS = (short*)smem + w * 1024;    // epilogue per-wave o_l scratch (over sK)

  // ---- prologue: stage pooled-k + q-pool partials ----
#pragma unroll
  for (int i = 0; i < 16; i++) {
    int o = t + i * 256;
    pkL[(o >> 6) * PSTR + (o & 63)] = pkw[(size_t)bh * 4096 + o];
  }
  {
    int c4 = t & 15, r0 = t >> 4;
    float4 sacc = {0.f, 0.f, 0.f, 0.f};
#pragma unroll
    for (int i = 0; i < 8; i++) {
      int row = m * 128 + r0 + i * 16;
      float4 xq = *(const float4*)(qin + (((size_t)b * LSEQ + row) * H_ + h) * D_ + c4 * 4);
      sacc.x += xq.x; sacc.y += xq.y; sacc.z += xq.z; sacc.w += xq.w;
    }
    qps[t] = sacc;
  }
  BLOCK_BARRIER();
  if (t < 64) {
    const float* qf = (const float*)qps;
    float sY = 0.f;
#pragma unroll
    for (int j = 0; j < 16; j++) sY += qf[j * 64 + t];
    pqL[t] = sY;
  }
  BLOCK_BARRIER();
  // ---- per-wave (redundant) score + top-6; lane == key-block ----
  float scv = 0.f;
  {
    const float* rowp = pkL + lane * PSTR;
#pragma unroll
    for (int d = 0; d < 64; d++) scv += pqL[d] * rowp[d];
  }
  int kbs_[TOPK];
#pragma unroll
  for (int r = 0; r < TOPK; r++) {
    float bs = scv; int bi = lane;
#pragma unroll
    for (int off = 32; off; off >>= 1) {
      float os = __shfl_xor(bs, off);
      int   oi = __shfl_xor(bi, off);
      if (os > bs || (os == bs && oi < bi)) { bs = os; bi = oi; }
    }
    int bsel = __builtin_amdgcn_readfirstlane(bi);  // lane-uniform -> SGPR
    kbs_[r] = bsel;                     // matches lax.top_k tie-break (lower idx first)
    if (lane == bsel) scv = -INFINITY;
  }
  BLOCK_BARRIER();   // all pkL/pqL reads done before ones-init overwrites [16384,16640)

  // ones rows d=64..79 of sV (never restaged)
  for (int i = t; i < 1024; i += 256) {
    int row = 64 + (i >> 6);
    sV[row * 64 + (i & 63)] = (row == 64) ? (short)0x3F80 : (short)0;
  }

  // ---- Q fragments (scaled by SCALE*log2e, single bf16) ----
  short8 qA[2][2];
#pragma unroll
  for (int mt = 0; mt < 2; mt++) {
    int qrow = m * 128 + w * 32 + mt * 16 + l15;
    const float* qp = qin + (((size_t)b * LSEQ + qrow) * H_ + h) * D_;
#pragma unroll
    for (int ks = 0; ks < 2; ks++) {
      int d0 = ks * 32 + quad * 8;
      float4 a0 = *(const float4*)(qp + d0);
      float4 a1 = *(const float4*)(qp + d0 + 4);
      union { int4 i; short8 s; } u;
      u.i.x = (int)pack2_rne(a0.x * SCL2, a0.y * SCL2);
      u.i.y = (int)pack2_rne(a0.z * SCL2, a0.w * SCL2);
      u.i.z = (int)pack2_rne(a1.x * SCL2, a1.y * SCL2);
      u.i.w = (int)pack2_rne(a1.z * SCL2, a1.w * SCL2);
      qA[mt][ks] = u.s;
    }
  }

  f32x4 O[2][4];
  f32x4 Lacc[2];
#pragma unroll
  for (int mt = 0; mt < 2; mt++) {
#pragma unroll
    for (int dt = 0; dt < 4; dt++) O[mt][dt] = (f32x4){0.f, 0.f, 0.f, 0.f};
    Lacc[mt] = (f32x4){0.f, 0.f, 0.f, 0.f};
  }

  // prefetch registers (raw fp32, packed at store time next iter)
  float4 pk0, pk1, pk2, pk3;   // K: thread (key=t>>2, c=t&3) 16 d's
  float4 pv0, pv1, pv2, pv3;   // V: keys (2*vj, 2*vj+1), d in [vd0, vd0+8)
  const int kkey = t >> 2, kc = t & 3;
  const int vj = t & 31, vd0 = (t >> 5) * 8;   // V pairing: 32 key-pairs x 8 d-octets

  {
    int kb = kbs_[0];
    const float* kp = kin + (((size_t)b * LSEQ + (size_t)kb * 64 + kkey) * H_ + h) * D_ + kc * 16;
    pk0 = *(const float4*)(kp + 0);  pk1 = *(const float4*)(kp + 4);
    pk2 = *(const float4*)(kp + 8);  pk3 = *(const float4*)(kp + 12);
    const float* vpE = vin + (((size_t)b * LSEQ + (size_t)kb * 64 + 2 * vj) * H_ + h) * D_ + vd0;
    pv0 = *(const float4*)(vpE + 0);       pv1 = *(const float4*)(vpE + 4);
    pv2 = *(const float4*)(vpE + H_ * D_); pv3 = *(const float4*)(vpE + H_ * D_ + 4);
  }

#pragma unroll
  for (int s = 0; s < TOPK; s++) {
    BLOCK_BARRIER();   // prev iter's LDS reads done (lgkm only — prefetch stays in flight)
    // ---- store prefetched K (pack + b128) ----
    {
      int4 h0, h1;
      h0.x = (int)pack2_rne(pk0.x, pk0.y);  h0.y = (int)pack2_rne(pk0.z, pk0.w);
      h0.z = (int)pack2_rne(pk1.x, pk1.y);  h0.w = (int)pack2_rne(pk1.z, pk1.w);
      h1.x = (int)pack2_rne(pk2.x, pk2.y);  h1.y = (int)pack2_rne(pk2.z, pk2.w);
      h1.z = (int)pack2_rne(pk3.x, pk3.y);  h1.w = (int)pack2_rne(pk3.z, pk3.w);
      int base = kkey * 64;
      int b0 = ((kc * 2    ) ^ (kkey & 7)) << 3;
      int b1 = ((kc * 2 + 1) ^ (kkey & 7)) << 3;
      *(int4*)(sK + base + b0) = h0;
      *(int4*)(sK + base + b1) = h1;
    }
    // ---- store prefetched V (paired bf16x2 transpose scatter) ----
    {
      float fa[8] = {pv0.x,pv0.y,pv0.z,pv0.w, pv1.x,pv1.y,pv1.z,pv1.w};  // key 2*vj
      float fb[8] = {pv2.x,pv2.y,pv2.z,pv2.w, pv3.x,pv3.y,pv3.z,pv3.w};  // key 2*vj+1
      int khi = (2 * vj) >> 3, klo = (2 * vj) & 7;   // klo even -> b32-aligned col
#pragma unroll
      for (int jj = 0; jj < 8; jj++) {
        int d = vd0 + jj;
        int col = ((khi ^ (d & 7)) << 3) | klo;
        *(unsigned*)(sV + d * 64 + col) = pack2_rne(fa[jj], fb[jj]);
      }
    }
    BLOCK_BARRIER();   // staged data visible (lgkm only)
    // ---- issue next iter's prefetch (overlaps with MFMA phase below) ----
    if (s + 1 < TOPK) {
      int kb = kbs_[s + 1];
      const float* kp = kin + (((size_t)b * LSEQ + (size_t)kb * 64 + kkey) * H_ + h) * D_ + kc * 16;
      pk0 = *(const float4*)(kp + 0);  pk1 = *(const float4*)(kp + 4);
      pk2 = *(const float4*)(kp + 8);  pk3 = *(const float4*)(kp + 12);
      const float* vpE = vin + (((size_t)b * LSEQ + (size_t)kb * 64 + 2 * vj) * H_ + h) * D_ + vd0;
      pv0 = *(const float4*)(vpE + 0);       pv1 = *(const float4*)(vpE + 4);
      pv2 = *(const float4*)(vpE + H_ * D_); pv3 = *(const float4*)(vpE + H_ * D_ + 4);
    }

#pragma unroll
    for (int mt = 0; mt < 2; mt++) {
      // ---- S = Q K^T (S is already *log2e scaled) ----
      f32x4 S[4];
      __builtin_amdgcn_s_setprio(1);
#pragma unroll
      for (int nt = 0; nt < 4; nt++) {
        f32x4 acc = (f32x4){0.f, 0.f, 0.f, 0.f};
        int row = nt * 16 + l15;
#pragma unroll
        for (int ks = 0; ks < 2; ks++) {
          int blk8 = ((ks * 4 + quad) ^ (row & 7)) << 3;
          short8 kh = *(const short8*)(sK + row * 64 + blk8);
          acc = __builtin_amdgcn_mfma_f32_16x16x32_bf16(qA[mt][ks], kh, acc, 0, 0, 0);
        }
        S[nt] = acc;
      }
      __builtin_amdgcn_s_setprio(0);
      // ---- p = exp2(S), wave-local transpose ----
#pragma unroll
      for (int r = 0; r < 4; r++) {
        int prow = quad * 4 + r;
#pragma unroll
        for (int nt = 0; nt < 4; nt++) {
          int key = nt * 16 + l15;
          int idx = prow * 64 + ((((key >> 3) ^ (prow & 7)) << 3) | (key & 7));
          wPs[idx] = bf16_rne(__builtin_amdgcn_exp2f(S[nt][r]));
        }
      }
      LGKM_FENCE();
      short8 pA[2];
#pragma unroll
      for (int ks = 0; ks < 2; ks++) {
        int blk8 = ((ks * 4 + quad) ^ (l15 & 7)) << 3;
        pA[ks] = *(const short8*)(wPs + l15 * 64 + blk8);
      }
      // (no fence needed after per-wave-scratch reads: same-wave LDS is in-order)
      // ---- O += P V  (dt=4 tile = ones row -> Lacc) ----
      __builtin_amdgcn_s_setprio(1);
#pragma unroll
      for (int dt = 0; dt < 5; dt++) {
        f32x4 acc = (dt < 4) ? O[mt][dt] : Lacc[mt];
        int row = dt * 16 + l15;
#pragma unroll
        for (int ks = 0; ks < 2; ks++) {
          int blk8 = ((ks * 4 + quad) ^ (row & 7)) << 3;
          short8 vh = *(const short8*)(sV + row * 64 + blk8);
          acc = __builtin_amdgcn_mfma_f32_16x16x32_bf16(pA[ks], vh, acc, 0, 0, 0);
        }
        if (dt < 4) O[mt][dt] = acc; else Lacc[mt] = acc;
      }
      __builtin_amdgcn_s_setprio(0);
    } // mt
  } // kblocks

  // ---- normalize o_s by l (l at l15==0 cols of each quad) ----
#pragma unroll
  for (int mt = 0; mt < 2; mt++)
#pragma unroll
    for (int r = 0; r < 4; r++) {
      float lv = __shfl(Lacc[mt][r], lane & 48);
      float inv = 1.f / lv;
#pragma unroll
      for (int dt = 0; dt < 4; dt++) O[mt][dt][r] *= inv;
    }

  // ---- epilogue: linear branch fused (qf from register Q-frags) ----
  BLOCK_BARRIER();   // main-loop LDS reads done; aliases writable
#pragma unroll
  for (int i = 0; i < 16; i++) {
    int idx = t + i * 256;
    int d = idx >> 6, e = idx & 63;
    int c1 = (((d >> 3) ^ (e & 7)) << 3) | (d & 7);
    skv[e * 64 + c1] = bf16_rne(kv[(size_t)bh * 4096 + idx]);
    int eo = idx >> 6, dd = idx & 63;
    int c2 = (((dd >> 3) ^ (eo & 7)) << 3) | (dd & 7);
    sW[eo * 64 + c2] = bf16_rne(Wg[idx]);
  }
#pragma unroll
  for (int j = 0; j < 4; j++) {
    int idx2 = t + j * 256;
    int row = 64 + (idx2 >> 6), col = idx2 & 63;
    skv[row * 64 + col] = (row == 64) ? bf16_rne(kfs[bh * 64 + col]) : (short)0;
  }
  if (t < 64) sbias[t] = biasg[t];
  BLOCK_BARRIER();

  const short8 onesB = {(short)0x3F80,(short)0x3F80,(short)0x3F80,(short)0x3F80,
                        (short)0x3F80,(short)0x3F80,(short)0x3F80,(short)0x3F80};

#pragma unroll
  for (int mt = 0; mt < 2; mt++) {
    // expq = e^q = exp2(8 * qA) elementwise (qA = q*0.125*log2e)
    float eq[2][8];
    short8 eqs[2];
#pragma unroll
    for (int ks = 0; ks < 2; ks++) {
      union { short8 s; short a[8]; } uu; uu.s = qA[mt][ks];
      union { int4 i; short8 s; } pp;
#pragma unroll
      for (int j = 0; j < 8; j++)
        eq[ks][j] = __builtin_amdgcn_exp2f(8.f * bf16_to_f32(uu.a[j]));
      pp.i.x = (int)pack2_rne(eq[ks][0], eq[ks][1]);
      pp.i.y = (int)pack2_rne(eq[ks][2], eq[ks][3]);
      pp.i.z = (int)pack2_rne(eq[ks][4], eq[ks][5]);
      pp.i.w = (int)pack2_rne(eq[ks][6], eq[ks][7]);
      eqs[ks] = pp.s;
    }
    // row sums via ones-B MFMA
    f32x4 ssv = (f32x4){0.f, 0.f, 0.f, 0.f};
    ssv = __builtin_amdgcn_mfma_f32_16x16x32_bf16(eqs[0], onesB, ssv, 0, 0, 0);
    ssv = __builtin_amdgcn_mfma_f32_16x16x32_bf16(eqs[1], onesB, ssv, 0, 0, 0);
    int srcl = (l15 >> 2) << 4;
    float s0 = __shfl(ssv[0], srcl);
    float s1 = __shfl(ssv[1], srcl);
    float s2 = __shfl(ssv[2], srcl);
    float s3 = __shfl(ssv[3], srcl);
    int rr = l15 & 3;
    float ssrow = (rr == 0) ? s0 : (rr == 1) ? s1 : (rr == 2) ? s2 : s3;
    float qinv = 1.f / ssrow;
    // qf A-frags
    short8 qf[2];
#pragma unroll
    for (int ks = 0; ks < 2; ks++) {
      union { int4 i; short8 s; } pp;
      pp.i.x = (int)pack2_rne(eq[ks][0] * qinv, eq[ks][1] * qinv);
      pp.i.y = (int)pack2_rne(eq[ks][2] * qinv, eq[ks][3] * qinv);
      pp.i.z = (int)pack2_rne(eq[ks][4] * qinv, eq[ks][5] * qinv);
      pp.i.w = (int)pack2_rne(eq[ks][6] * qinv, eq[ks][7] * qinv);
      qf[ks] = pp.s;
    }
    // num (nt 0..3) and den (nt=4, kfs row)
    f32x4 Cn[5];
#pragma unroll
    for (int nt = 0; nt < 5; nt++) {
      f32x4 acc = (f32x4){0.f, 0.f, 0.f, 0.f};
      int row = nt * 16 + l15;
#pragma unroll
      for (int ks = 0; ks < 2; ks++) {
        int blk8 = ((ks * 4 + quad) ^ (row & 7)) << 3;
        short8 bf = *(const short8*)(skv + row * 64 + blk8);
        acc = __builtin_amdgcn_mfma_f32_16x16x32_bf16(qf[ks], bf, acc, 0, 0, 0);
      }
      Cn[nt] = acc;
    }
    // o_l = num / (eps + den) -> wave-local transpose
#pragma unroll
    for (int r = 0; r < 4; r++) {
      float dv = __shfl(Cn[4][r], lane & 48);
      float invd = 1.f / (EPSL + dv);
      int prow = quad * 4 + r;
#pragma unroll
      for (int nt = 0; nt < 4; nt++) {
        int e = nt * 16 + l15;
        int idx = prow * 64 + ((((e >> 3) ^ (prow & 7)) << 3) | (e & 7));
        olS[idx] = bf16_rne(Cn[nt][r] * invd);
      }
    }
    LGKM_FENCE();
    short8 oh[2];
#pragma unroll
    for (int ks = 0; ks < 2; ks++) {
      int blk8 = ((ks * 4 + quad) ^ (l15 & 7)) << 3;
      oh[ks] = *(const short8*)(olS + l15 * 64 + blk8);
    }
    // (no fence needed after per-wave-scratch reads)
    // O += o_l @ W^T
#pragma unroll
    for (int nt = 0; nt < 4; nt++) {
      int row = nt * 16 + l15;
      f32x4 acc = O[mt][nt];
#pragma unroll
      for (int ks = 0; ks < 2; ks++) {
        int blk8 = ((ks * 4 + quad) ^ (row & 7)) << 3;
        short8 wf = *(const short8*)(sW + row * 64 + blk8);
        acc = __builtin_amdgcn_mfma_f32_16x16x32_bf16(oh[ks], wf, acc, 0, 0, 0);
      }
      O[mt][nt] = acc;
    }
  }

  // ---- store out = o_s + o_l + bias ----
#pragma unroll
  for (int mt = 0; mt < 2; mt++) {
    int qrow0 = m * 128 + w * 32 + mt * 16 + quad * 4;
#pragma unroll
    for (int r = 0; r < 4; r++) {
      float* op = out + (((size_t)b * LSEQ + qrow0 + r) * H_ + h) * D_ + l15;
#pragma unroll
      for (int dt = 0; dt < 4; dt++)
        op[dt * 16] = O[mt][dt][r] + sbias[dt * 16 + l15];
    }
  }
}

extern "C" void kernel_launch(void* const* d_in, const int* in_sizes, int n_in,
                              void* d_out, int out_size, void* d_ws, size_t ws_size,
                              hipStream_t stream)
{
  const float* q    = (const float*)d_in[0];
  const float* k    = (const float*)d_in[1];
  const float* v    = (const float*)d_in[2];
  const float* W    = (const float*)d_in[3];
  const float* bias = (const float*)d_in[4];
  float* out = (float*)d_out;

  float* kv  = (float*)d_ws;                               // B*H*64*64
  float* kfs = kv  + (size_t)B_ * H_ * D_ * D_;            // B*H*64
  float* pkw = kfs + (size_t)B_ * H_ * D_;                 // B*H*64*64

  size_t zero_bytes = ((size_t)B_ * H_ * D_ * D_ + (size_t)B_ * H_ * D_) * sizeof(float);
  (void)hipMemsetAsync(d_ws, 0, zero_bytes, stream);

  hipLaunchKernelGGL(lin_stats_kernel,  dim3(B_ * H_ * SPLIT), dim3(256), 0, stream,
                     k, v, kv, kfs, pkw);
  hipLaunchKernelGGL(sparse_attn_kernel,dim3(B_ * H_ * M_),    dim3(256), 0, stream,
                     q, k, v, pkw, kv, kfs, W, bias, out);
}